// Round 1
// baseline (1031.597 us; speedup 1.0000x reference)
//
#include <hip/hip_runtime.h>
#include <cmath>

typedef __attribute__((ext_vector_type(8))) short bf16x8;
typedef __attribute__((ext_vector_type(4))) float f32x4;
typedef unsigned short u16;

struct __align__(8) us4 { u16 x, y, z, w; };

__device__ __forceinline__ u16 f2bf(float f) {
    union { float f; unsigned u; } v; v.f = f;
    unsigned u = v.u;
    u += 0x7fffu + ((u >> 16) & 1u);   // RNE
    return (u16)(u >> 16);
}
__device__ __forceinline__ float bf2f(u16 h) {
    union { unsigned u; float f; } v; v.u = ((unsigned)h) << 16;
    return v.f;
}
__device__ __forceinline__ f32x4 mfma16(bf16x8 a, bf16x8 b, f32x4 c) {
    return __builtin_amdgcn_mfma_f32_16x16x32_bf16(a, b, c, 0, 0, 0);
}

// ---------------- fp32 -> bf16 conversion (vectorized x4) ----------------
__global__ __launch_bounds__(256) void cvt4(const float* __restrict__ in,
                                            u16* __restrict__ out, int n4) {
    int i = blockIdx.x * 256 + threadIdx.x;
    if (i >= n4) return;
    float4 f = reinterpret_cast<const float4*>(in)[i];
    us4 o; o.x = f2bf(f.x); o.y = f2bf(f.y); o.z = f2bf(f.z); o.w = f2bf(f.w);
    reinterpret_cast<us4*>(out)[i] = o;
}

// ---------------- K1: feat_proj = X @ W_fc^T + b_fc, stored transposed bf16 ----------------
// fpT[b][e][n]  (per batch: 768 x 1024)
__global__ __launch_bounds__(256) void k_fc(const u16* __restrict__ Xb,
                                            const u16* __restrict__ Wfc,
                                            const float* __restrict__ bfc,
                                            u16* __restrict__ fpT) {
    const int lane = threadIdx.x & 63;
    const int wave = threadIdx.x >> 6;
    const int lm = lane & 15, quad = lane >> 4;
    const int row0 = blockIdx.x * 128 + (wave & 1) * 64;
    const int col0 = blockIdx.y * 128 + (wave >> 1) * 64;

    const u16* ap[4]; const u16* bp[4];
#pragma unroll
    for (int i = 0; i < 4; i++) ap[i] = Xb + (size_t)(row0 + i * 16 + lm) * 768 + quad * 8;
#pragma unroll
    for (int j = 0; j < 4; j++) bp[j] = Wfc + (size_t)(col0 + j * 16 + lm) * 768 + quad * 8;

    f32x4 acc[4][4] = {};
    for (int k = 0; k < 768; k += 32) {
        bf16x8 a[4], b[4];
#pragma unroll
        for (int i = 0; i < 4; i++) { a[i] = *reinterpret_cast<const bf16x8*>(ap[i]); ap[i] += 32; }
#pragma unroll
        for (int j = 0; j < 4; j++) { b[j] = *reinterpret_cast<const bf16x8*>(bp[j]); bp[j] += 32; }
#pragma unroll
        for (int i = 0; i < 4; i++)
#pragma unroll
            for (int j = 0; j < 4; j++)
                acc[i][j] = mfma16(a[i], b[j], acc[i][j]);
    }
#pragma unroll
    for (int i = 0; i < 4; i++) {
        int rbase = row0 + i * 16 + quad * 4;
        int bb = rbase >> 10, nn = rbase & 1023;
#pragma unroll
        for (int j = 0; j < 4; j++) {
            int col = col0 + j * 16 + lm;
            float bias = bfc[col];
            us4 o;
            o.x = f2bf(acc[i][j][0] + bias);
            o.y = f2bf(acc[i][j][1] + bias);
            o.z = f2bf(acc[i][j][2] + bias);
            o.w = f2bf(acc[i][j][3] + bias);
            *reinterpret_cast<us4*>(fpT + (size_t)bb * 786432 + (size_t)col * 1024 + nn) = o;
        }
    }
}

// ---------------- K2: q/k vectors from fpT ----------------
__global__ __launch_bounds__(64) void k_qk(const u16* __restrict__ fpT,
                                           const float* __restrict__ wq, const float* __restrict__ bq,
                                           const float* __restrict__ wk, const float* __restrict__ bk,
                                           float* __restrict__ qv, float* __restrict__ kv) {
    int m = blockIdx.x * 64 + threadIdx.x;
    int b = m >> 10, n = m & 1023;
    const u16* base = fpT + (size_t)b * 786432 + n;
    float sq = 0.f, sk = 0.f;
#pragma unroll 8
    for (int d = 0; d < 768; d++) {
        float f = bf2f(base[(size_t)d << 10]);
        sq = fmaf(f, wq[d], sq);
        sk = fmaf(f, wk[d], sk);
    }
    qv[m] = sq + bq[0];
    kv[m] = sk + bk[0];
}

// ---------------- K3: masked leaky-relu softmax rows -> att (bf16) ----------------
__global__ __launch_bounds__(256) void k_soft(const float* __restrict__ adj,
                                              const float* __restrict__ qv,
                                              const float* __restrict__ kv,
                                              u16* __restrict__ attb) {
    int bn = blockIdx.x;               // b*1024 + n
    int b = bn >> 10;
    const float* adjrow = adj + (size_t)bn * 1024;
    const float* krow = kv + (b << 10);
    float q = qv[bn];
    int m0 = threadIdx.x * 4;

    float4 a4 = *reinterpret_cast<const float4*>(adjrow + m0);
    float4 k4 = *reinterpret_cast<const float4*>(krow + m0);
    float v[4];
    v[0] = q + k4.x + (1.f - a4.x) * -1.0e9f;
    v[1] = q + k4.y + (1.f - a4.y) * -1.0e9f;
    v[2] = q + k4.z + (1.f - a4.z) * -1.0e9f;
    v[3] = q + k4.w + (1.f - a4.w) * -1.0e9f;
#pragma unroll
    for (int t = 0; t < 4; t++) v[t] = v[t] >= 0.f ? v[t] : 0.01f * v[t];

    float mx = fmaxf(fmaxf(v[0], v[1]), fmaxf(v[2], v[3]));
    __shared__ float red[4];
#pragma unroll
    for (int off = 32; off; off >>= 1) mx = fmaxf(mx, __shfl_xor(mx, off));
    if ((threadIdx.x & 63) == 0) red[threadIdx.x >> 6] = mx;
    __syncthreads();
    mx = fmaxf(fmaxf(red[0], red[1]), fmaxf(red[2], red[3]));

    float s = 0.f;
#pragma unroll
    for (int t = 0; t < 4; t++) { v[t] = __expf(v[t] - mx); s += v[t]; }
#pragma unroll
    for (int off = 32; off; off >>= 1) s += __shfl_xor(s, off);
    __syncthreads();
    if ((threadIdx.x & 63) == 0) red[threadIdx.x >> 6] = s;
    __syncthreads();
    s = red[0] + red[1] + red[2] + red[3];
    float inv = 1.f / s;

    us4 o;
    o.x = f2bf(v[0] * inv); o.y = f2bf(v[1] * inv);
    o.z = f2bf(v[2] * inv); o.w = f2bf(v[3] * inv);
    *reinterpret_cast<us4*>(attb + (size_t)bn * 1024 + m0) = o;
}

// ---------------- K4: y = att @ feat_proj (batched), yb bf16 [m][d] ----------------
__global__ __launch_bounds__(256) void k_av(const u16* __restrict__ attb,
                                            const u16* __restrict__ fpT,
                                            u16* __restrict__ yb) {
    int b = blockIdx.z;
    const u16* A  = attb + (size_t)b * 1048576;
    const u16* Bw = fpT + (size_t)b * 786432;
    const int lane = threadIdx.x & 63;
    const int wave = threadIdx.x >> 6;
    const int lm = lane & 15, quad = lane >> 4;
    const int row0 = blockIdx.x * 128 + (wave & 1) * 64;
    const int col0 = blockIdx.y * 128 + (wave >> 1) * 64;

    const u16* ap[4]; const u16* bp[4];
#pragma unroll
    for (int i = 0; i < 4; i++) ap[i] = A + (size_t)(row0 + i * 16 + lm) * 1024 + quad * 8;
#pragma unroll
    for (int j = 0; j < 4; j++) bp[j] = Bw + (size_t)(col0 + j * 16 + lm) * 1024 + quad * 8;

    f32x4 acc[4][4] = {};
    for (int k = 0; k < 1024; k += 32) {
        bf16x8 a[4], b4[4];
#pragma unroll
        for (int i = 0; i < 4; i++) { a[i] = *reinterpret_cast<const bf16x8*>(ap[i]); ap[i] += 32; }
#pragma unroll
        for (int j = 0; j < 4; j++) { b4[j] = *reinterpret_cast<const bf16x8*>(bp[j]); bp[j] += 32; }
#pragma unroll
        for (int i = 0; i < 4; i++)
#pragma unroll
            for (int j = 0; j < 4; j++)
                acc[i][j] = mfma16(a[i], b4[j], acc[i][j]);
    }
#pragma unroll
    for (int i = 0; i < 4; i++) {
        int rbase = row0 + i * 16 + quad * 4;
#pragma unroll
        for (int j = 0; j < 4; j++) {
            int col = col0 + j * 16 + lm;
#pragma unroll
            for (int r = 0; r < 4; r++)
                yb[(size_t)(b * 1024 + rbase + r) * 768 + col] = f2bf(acc[i][j][r]);
        }
    }
}

// ---------------- K5: fused gate pre-activations ----------------
// U = y@Wuy^T + x@Wux^T (+b), R likewise, Ty = y@Wty^T (+b)
// writes u_ws (fp32 sigmoid), rxb (bf16 r*x), ty_ws (fp32)
__global__ __launch_bounds__(256) void k_gates(const u16* __restrict__ yb, const u16* __restrict__ Xb,
                                               const u16* __restrict__ Wuy, const u16* __restrict__ Wux,
                                               const u16* __restrict__ Wry, const u16* __restrict__ Wrx,
                                               const u16* __restrict__ Wty,
                                               const float* __restrict__ buy, const float* __restrict__ bux,
                                               const float* __restrict__ bry, const float* __restrict__ brx,
                                               const float* __restrict__ bty,
                                               const float* __restrict__ xin,
                                               float* __restrict__ u_ws, u16* __restrict__ rxb,
                                               float* __restrict__ ty_ws) {
    const int lane = threadIdx.x & 63;
    const int wave = threadIdx.x >> 6;
    const int lm = lane & 15, quad = lane >> 4;
    const int row0 = blockIdx.x * 128 + wave * 32;
    const int col0 = blockIdx.y * 32;

    f32x4 aU[2][2] = {}, aR[2][2] = {}, aT[2][2] = {};

    {   // phase 1: A = y
        const u16* a0p = yb + (size_t)(row0 + lm) * 768 + quad * 8;
        const u16* a1p = a0p + 16 * 768;
        const u16* u0p = Wuy + (size_t)(col0 + lm) * 768 + quad * 8;
        const u16* u1p = u0p + 16 * 768;
        const u16* r0p = Wry + (size_t)(col0 + lm) * 768 + quad * 8;
        const u16* r1p = r0p + 16 * 768;
        const u16* t0p = Wty + (size_t)(col0 + lm) * 768 + quad * 8;
        const u16* t1p = t0p + 16 * 768;
        for (int k = 0; k < 768; k += 32) {
            bf16x8 a0 = *reinterpret_cast<const bf16x8*>(a0p);
            bf16x8 a1 = *reinterpret_cast<const bf16x8*>(a1p);
            bf16x8 bu0 = *reinterpret_cast<const bf16x8*>(u0p);
            bf16x8 bu1 = *reinterpret_cast<const bf16x8*>(u1p);
            bf16x8 br0 = *reinterpret_cast<const bf16x8*>(r0p);
            bf16x8 br1 = *reinterpret_cast<const bf16x8*>(r1p);
            bf16x8 bt0 = *reinterpret_cast<const bf16x8*>(t0p);
            bf16x8 bt1 = *reinterpret_cast<const bf16x8*>(t1p);
            aU[0][0] = mfma16(a0, bu0, aU[0][0]); aU[0][1] = mfma16(a0, bu1, aU[0][1]);
            aU[1][0] = mfma16(a1, bu0, aU[1][0]); aU[1][1] = mfma16(a1, bu1, aU[1][1]);
            aR[0][0] = mfma16(a0, br0, aR[0][0]); aR[0][1] = mfma16(a0, br1, aR[0][1]);
            aR[1][0] = mfma16(a1, br0, aR[1][0]); aR[1][1] = mfma16(a1, br1, aR[1][1]);
            aT[0][0] = mfma16(a0, bt0, aT[0][0]); aT[0][1] = mfma16(a0, bt1, aT[0][1]);
            aT[1][0] = mfma16(a1, bt0, aT[1][0]); aT[1][1] = mfma16(a1, bt1, aT[1][1]);
            a0p += 32; a1p += 32; u0p += 32; u1p += 32; r0p += 32; r1p += 32; t0p += 32; t1p += 32;
        }
    }
    {   // phase 2: A = x
        const u16* a0p = Xb + (size_t)(row0 + lm) * 768 + quad * 8;
        const u16* a1p = a0p + 16 * 768;
        const u16* u0p = Wux + (size_t)(col0 + lm) * 768 + quad * 8;
        const u16* u1p = u0p + 16 * 768;
        const u16* r0p = Wrx + (size_t)(col0 + lm) * 768 + quad * 8;
        const u16* r1p = r0p + 16 * 768;
        for (int k = 0; k < 768; k += 32) {
            bf16x8 a0 = *reinterpret_cast<const bf16x8*>(a0p);
            bf16x8 a1 = *reinterpret_cast<const bf16x8*>(a1p);
            bf16x8 bu0 = *reinterpret_cast<const bf16x8*>(u0p);
            bf16x8 bu1 = *reinterpret_cast<const bf16x8*>(u1p);
            bf16x8 br0 = *reinterpret_cast<const bf16x8*>(r0p);
            bf16x8 br1 = *reinterpret_cast<const bf16x8*>(r1p);
            aU[0][0] = mfma16(a0, bu0, aU[0][0]); aU[0][1] = mfma16(a0, bu1, aU[0][1]);
            aU[1][0] = mfma16(a1, bu0, aU[1][0]); aU[1][1] = mfma16(a1, bu1, aU[1][1]);
            aR[0][0] = mfma16(a0, br0, aR[0][0]); aR[0][1] = mfma16(a0, br1, aR[0][1]);
            aR[1][0] = mfma16(a1, br0, aR[1][0]); aR[1][1] = mfma16(a1, br1, aR[1][1]);
            a0p += 32; a1p += 32; u0p += 32; u1p += 32; r0p += 32; r1p += 32;
        }
    }
#pragma unroll
    for (int i = 0; i < 2; i++) {
        int rbase = row0 + i * 16 + quad * 4;
#pragma unroll
        for (int j = 0; j < 2; j++) {
            int col = col0 + j * 16 + lm;
            float bU = buy[col] + bux[col];
            float bR = bry[col] + brx[col];
            float bT = bty[col];
#pragma unroll
            for (int r = 0; r < 4; r++) {
                size_t idx = (size_t)(rbase + r) * 768 + col;
                float uu = 1.f / (1.f + __expf(-(aU[i][j][r] + bU)));
                u_ws[idx] = uu;
                float rr = 1.f / (1.f + __expf(-(aR[i][j][r] + bR)));
                rxb[idx] = f2bf(rr * xin[idx]);
                ty_ws[idx] = aT[i][j][r] + bT;
            }
        }
    }
}

// ---------------- K6: T = Ty + (r*x)@Wtx^T + b_tx; out = (1-u)x + u*tanh(T) ----------------
__global__ __launch_bounds__(256) void k_out(const u16* __restrict__ rxb, const u16* __restrict__ Wtx,
                                             const float* __restrict__ btx,
                                             const float* __restrict__ ty_ws,
                                             const float* __restrict__ u_ws,
                                             const float* __restrict__ xin,
                                             float* __restrict__ out) {
    const int lane = threadIdx.x & 63;
    const int wave = threadIdx.x >> 6;
    const int lm = lane & 15, quad = lane >> 4;
    const int row0 = blockIdx.x * 128 + (wave & 1) * 64;
    const int col0 = blockIdx.y * 128 + (wave >> 1) * 64;

    const u16* ap[4]; const u16* bp[4];
#pragma unroll
    for (int i = 0; i < 4; i++) ap[i] = rxb + (size_t)(row0 + i * 16 + lm) * 768 + quad * 8;
#pragma unroll
    for (int j = 0; j < 4; j++) bp[j] = Wtx + (size_t)(col0 + j * 16 + lm) * 768 + quad * 8;

    f32x4 acc[4][4] = {};
    for (int k = 0; k < 768; k += 32) {
        bf16x8 a[4], b4[4];
#pragma unroll
        for (int i = 0; i < 4; i++) { a[i] = *reinterpret_cast<const bf16x8*>(ap[i]); ap[i] += 32; }
#pragma unroll
        for (int j = 0; j < 4; j++) { b4[j] = *reinterpret_cast<const bf16x8*>(bp[j]); bp[j] += 32; }
#pragma unroll
        for (int i = 0; i < 4; i++)
#pragma unroll
            for (int j = 0; j < 4; j++)
                acc[i][j] = mfma16(a[i], b4[j], acc[i][j]);
    }
#pragma unroll
    for (int i = 0; i < 4; i++) {
        int rbase = row0 + i * 16 + quad * 4;
#pragma unroll
        for (int j = 0; j < 4; j++) {
            int col = col0 + j * 16 + lm;
            float bias = btx[col];
#pragma unroll
            for (int r = 0; r < 4; r++) {
                size_t idx = (size_t)(rbase + r) * 768 + col;
                float t = tanhf(acc[i][j][r] + bias + ty_ws[idx]);
                float uu = u_ws[idx];
                float xv = xin[idx];
                out[idx] = (1.f - uu) * xv + uu * t;
            }
        }
    }
}

extern "C" void kernel_launch(void* const* d_in, const int* in_sizes, int n_in,
                              void* d_out, int out_size, void* d_ws, size_t ws_size,
                              hipStream_t stream) {
    const float* x    = (const float*)d_in[0];
    const float* adj  = (const float*)d_in[1];
    const float* W_fc = (const float*)d_in[2];
    const float* b_fc = (const float*)d_in[3];
    const float* w_q  = (const float*)d_in[4];
    const float* b_q  = (const float*)d_in[5];
    const float* w_k  = (const float*)d_in[6];
    const float* b_k  = (const float*)d_in[7];
    const float* W_uy = (const float*)d_in[8];
    const float* b_uy = (const float*)d_in[9];
    const float* W_ux = (const float*)d_in[10];
    const float* b_ux = (const float*)d_in[11];
    const float* W_ry = (const float*)d_in[12];
    const float* b_ry = (const float*)d_in[13];
    const float* W_rx = (const float*)d_in[14];
    const float* b_rx = (const float*)d_in[15];
    const float* W_ty = (const float*)d_in[16];
    const float* b_ty = (const float*)d_in[17];
    const float* W_tx = (const float*)d_in[18];
    const float* b_tx = (const float*)d_in[19];

    char* ws = (char*)d_ws;
    // workspace layout (bytes), total 200 MiB
    u16*   Xb    = (u16*)  (ws + 0);            // 16384x768 bf16      = 25165824
    u16*   Wb    = (u16*)  (ws + 25165824);     // 7 x 768x768 bf16    =  8257536
    u16*   fpT   = (u16*)  (ws + 33423360);     // 16x768x1024 bf16    = 25165824
    float* qv    = (float*)(ws + 58589184);     // 16384 f32           =    65536
    float* kv    = (float*)(ws + 58654720);     // 16384 f32           =    65536
    u16*   attb  = (u16*)  (ws + 58720256);     // 16x1024x1024 bf16   = 33554432
    float* u_ws  = (float*)(ws + 58720256);     // aliases attb (att dead after k_av)
    u16*   yb    = (u16*)  (ws + 109051904);    // 16384x768 bf16      = 25165824
    float* ty_ws = (float*)(ws + 134217728);    // 16384x768 f32       = 50331648
    u16*   rxb   = (u16*)  (ws + 184549376);    // 16384x768 bf16      = 25165824

    u16* Wfc_b = Wb + 0 * 589824;
    u16* Wuy_b = Wb + 1 * 589824;
    u16* Wux_b = Wb + 2 * 589824;
    u16* Wry_b = Wb + 3 * 589824;
    u16* Wrx_b = Wb + 4 * 589824;
    u16* Wty_b = Wb + 5 * 589824;
    u16* Wtx_b = Wb + 6 * 589824;

    cvt4<<<12288, 256, 0, stream>>>(x, Xb, 3145728);
    cvt4<<<576, 256, 0, stream>>>(W_fc, Wfc_b, 147456);
    cvt4<<<576, 256, 0, stream>>>(W_uy, Wuy_b, 147456);
    cvt4<<<576, 256, 0, stream>>>(W_ux, Wux_b, 147456);
    cvt4<<<576, 256, 0, stream>>>(W_ry, Wry_b, 147456);
    cvt4<<<576, 256, 0, stream>>>(W_rx, Wrx_b, 147456);
    cvt4<<<576, 256, 0, stream>>>(W_ty, Wty_b, 147456);
    cvt4<<<576, 256, 0, stream>>>(W_tx, Wtx_b, 147456);

    k_fc<<<dim3(128, 6), 256, 0, stream>>>(Xb, Wfc_b, b_fc, fpT);
    k_qk<<<256, 64, 0, stream>>>(fpT, w_q, b_q, w_k, b_k, qv, kv);
    k_soft<<<16384, 256, 0, stream>>>(adj, qv, kv, attb);
    k_av<<<dim3(8, 6, 16), 256, 0, stream>>>(attb, fpT, yb);
    k_gates<<<dim3(128, 24), 256, 0, stream>>>(yb, Xb, Wuy_b, Wux_b, Wry_b, Wrx_b, Wty_b,
                                               b_uy, b_ux, b_ry, b_rx, b_ty, x,
                                               u_ws, rxb, ty_ws);
    k_out<<<dim3(128, 6), 256, 0, stream>>>(rxb, Wtx_b, b_tx, ty_ws, u_ws, x, (float*)d_out);
}

// Round 2
// 575.465 us; speedup vs baseline: 1.7926x; 1.7926x over previous
//
#include <hip/hip_runtime.h>
#include <cmath>

typedef __attribute__((ext_vector_type(8))) short bf16x8;
typedef __attribute__((ext_vector_type(4))) float f32x4;
typedef unsigned short u16;

struct __align__(8) us4 { u16 x, y, z, w; };

__device__ __forceinline__ u16 f2bf(float f) {
    union { float f; unsigned u; } v; v.f = f;
    unsigned u = v.u;
    u += 0x7fffu + ((u >> 16) & 1u);   // RNE
    return (u16)(u >> 16);
}
__device__ __forceinline__ float bf2f(u16 h) {
    union { unsigned u; float f; } v; v.u = ((unsigned)h) << 16;
    return v.f;
}
__device__ __forceinline__ f32x4 mfma16(bf16x8 a, bf16x8 b, f32x4 c) {
    return __builtin_amdgcn_mfma_f32_16x16x32_bf16(a, b, c, 0, 0, 0);
}
// async global->LDS, 16 B per lane. LDS dest is wave-uniform base + lane*16.
__device__ __forceinline__ void ld_lds16(const u16* g, u16* l) {
    __builtin_amdgcn_global_load_lds(
        (const __attribute__((address_space(1))) unsigned int*)g,
        (__attribute__((address_space(3))) unsigned int*)l, 16, 0, 0);
}

// ---------------- fp32 -> bf16 conversion (vectorized x4) ----------------
__global__ __launch_bounds__(256) void cvt4(const float* __restrict__ in,
                                            u16* __restrict__ out, int n4) {
    int i = blockIdx.x * 256 + threadIdx.x;
    if (i >= n4) return;
    float4 f = reinterpret_cast<const float4*>(in)[i];
    us4 o; o.x = f2bf(f.x); o.y = f2bf(f.y); o.z = f2bf(f.z); o.w = f2bf(f.w);
    reinterpret_cast<us4*>(out)[i] = o;
}

// =====================================================================
// Unified m97-style GEMM: C[128x128 tile] = A @ B^T (+ phase2 A2 @ B2^T)
// A: row-major [M x K] (row stride ldA elems), B passed as B^T row-major
// [N x K] (row stride ldB). 256 threads, 4 waves, each wave 64x64 out.
// BK=32, LDS 8KB+8KB staged via global_load_lds width 16.
// =====================================================================
enum { EPI_FPT = 0, EPI_Y, EPI_U, EPI_RX, EPI_T, EPI_OUT };

struct Epi {
    const float* b1; const float* b2;
    const float* xin; const float* ty; const float* u;
    float* of; u16* ob; u16* fpT;
};

template<int EPI, int PH>
__global__ __launch_bounds__(256) void g128(
    const u16* __restrict__ A1, const u16* __restrict__ B1,
    const u16* __restrict__ A2, const u16* __restrict__ B2,
    int K, int ldA, int ldB,
    size_t zA, size_t zB, int zRows, Epi e)
{
    __shared__ u16 lA[128 * 32];
    __shared__ u16 lB[128 * 32];

    const int t = threadIdx.x;
    const int w = t >> 6, lane = t & 63, lm = lane & 15, quad = lane >> 4;
    const int row0 = blockIdx.x * 128, col0 = blockIdx.y * 128;

    // staging map: instr q in {0,1}: covers tile rows r = q*64 + t/4, k-chunk (t&3)*8
    const int rs = t >> 2, kc = (t & 3) * 8;
    u16* dA0 = lA + w * 512;           // wave-uniform LDS bases
    u16* dA1 = lA + 2048 + w * 512;
    u16* dB0 = lB + w * 512;
    u16* dB1 = lB + 2048 + w * 512;

    // per-wave compute map: wave (w&1) rows, (w>>1) cols
    const int rw0 = (w & 1) * 64, cw0 = (w >> 1) * 64;
    const u16* la[4]; const u16* lb[4];
#pragma unroll
    for (int i = 0; i < 4; i++) la[i] = lA + (rw0 + i * 16 + lm) * 32 + quad * 8;
#pragma unroll
    for (int j = 0; j < 4; j++) lb[j] = lB + (cw0 + j * 16 + lm) * 32 + quad * 8;

    f32x4 acc[4][4] = {};

#pragma unroll
    for (int ph = 0; ph < PH; ph++) {
        const u16* As = (ph == 0) ? A1 + (size_t)blockIdx.z * zA : A2;
        const u16* Bs = (ph == 0) ? B1 + (size_t)blockIdx.z * zB : B2;
        const u16* gA0 = As + (size_t)(row0 + rs) * ldA + kc;
        const u16* gA1 = As + (size_t)(row0 + 64 + rs) * ldA + kc;
        const u16* gB0 = Bs + (size_t)(col0 + rs) * ldB + kc;
        const u16* gB1 = Bs + (size_t)(col0 + 64 + rs) * ldB + kc;

        for (int k0 = 0; k0 < K; k0 += 32) {
            if (k0 != 0 || ph != 0) __syncthreads();   // LDS safe to overwrite
            ld_lds16(gA0 + k0, dA0);
            ld_lds16(gA1 + k0, dA1);
            ld_lds16(gB0 + k0, dB0);
            ld_lds16(gB1 + k0, dB1);
            __syncthreads();                            // drains vmcnt -> LDS ready

            bf16x8 a[4], b[4];
#pragma unroll
            for (int i = 0; i < 4; i++) a[i] = *reinterpret_cast<const bf16x8*>(la[i]);
#pragma unroll
            for (int j = 0; j < 4; j++) b[j] = *reinterpret_cast<const bf16x8*>(lb[j]);
#pragma unroll
            for (int i = 0; i < 4; i++)
#pragma unroll
                for (int j = 0; j < 4; j++)
                    acc[i][j] = mfma16(a[i], b[j], acc[i][j]);
        }
    }

    // ---------------- epilogue ----------------
#pragma unroll
    for (int i = 0; i < 4; i++) {
        const int gr = blockIdx.z * zRows + row0 + rw0 + i * 16 + quad * 4;
#pragma unroll
        for (int j = 0; j < 4; j++) {
            const int gc = col0 + cw0 + j * 16 + lm;
            if constexpr (EPI == EPI_FPT) {
                float bias = e.b1[gc];
                int bb = gr >> 10, nn = gr & 1023;
                us4 o;
                o.x = f2bf(acc[i][j][0] + bias);
                o.y = f2bf(acc[i][j][1] + bias);
                o.z = f2bf(acc[i][j][2] + bias);
                o.w = f2bf(acc[i][j][3] + bias);
                *reinterpret_cast<us4*>(e.fpT + (size_t)bb * 786432 + (size_t)gc * 1024 + nn) = o;
            } else if constexpr (EPI == EPI_Y) {
#pragma unroll
                for (int r = 0; r < 4; r++)
                    e.ob[(size_t)(gr + r) * 768 + gc] = f2bf(acc[i][j][r]);
            } else if constexpr (EPI == EPI_U) {
                float bias = e.b1[gc] + e.b2[gc];
#pragma unroll
                for (int r = 0; r < 4; r++) {
                    size_t idx = (size_t)(gr + r) * 768 + gc;
                    e.of[idx] = 1.f / (1.f + __expf(-(acc[i][j][r] + bias)));
                }
            } else if constexpr (EPI == EPI_RX) {
                float bias = e.b1[gc] + e.b2[gc];
#pragma unroll
                for (int r = 0; r < 4; r++) {
                    size_t idx = (size_t)(gr + r) * 768 + gc;
                    float rr = 1.f / (1.f + __expf(-(acc[i][j][r] + bias)));
                    e.ob[idx] = f2bf(rr * e.xin[idx]);
                }
            } else if constexpr (EPI == EPI_T) {
                float bias = e.b1[gc];
#pragma unroll
                for (int r = 0; r < 4; r++) {
                    size_t idx = (size_t)(gr + r) * 768 + gc;
                    e.of[idx] = acc[i][j][r] + bias;
                }
            } else {  // EPI_OUT
                float bias = e.b1[gc];
#pragma unroll
                for (int r = 0; r < 4; r++) {
                    size_t idx = (size_t)(gr + r) * 768 + gc;
                    float tt = tanhf(acc[i][j][r] + bias + e.ty[idx]);
                    float uu = e.u[idx];
                    float xv = e.xin[idx];
                    e.of[idx] = (1.f - uu) * xv + uu * tt;
                }
            }
        }
    }
}

// ---------------- q/k vectors from fpT (coalesced across lanes) ----------------
__global__ __launch_bounds__(256) void k_qk(const u16* __restrict__ fpT,
                                            const float* __restrict__ wq, const float* __restrict__ bq,
                                            const float* __restrict__ wk, const float* __restrict__ bk,
                                            float* __restrict__ qv, float* __restrict__ kv) {
    int m = blockIdx.x * 256 + threadIdx.x;
    int b = m >> 10, n = m & 1023;
    const u16* base = fpT + (size_t)b * 786432 + n;
    float sq = 0.f, sk = 0.f;
#pragma unroll 16
    for (int d = 0; d < 768; d++) {
        float f = bf2f(base[(size_t)d << 10]);
        sq = fmaf(f, wq[d], sq);
        sk = fmaf(f, wk[d], sk);
    }
    qv[m] = sq + bq[0];
    kv[m] = sk + bk[0];
}

// ---------------- masked leaky-relu softmax rows -> att (bf16) ----------------
__global__ __launch_bounds__(256) void k_soft(const float* __restrict__ adj,
                                              const float* __restrict__ qv,
                                              const float* __restrict__ kv,
                                              u16* __restrict__ attb) {
    int bn = blockIdx.x;               // b*1024 + n
    int b = bn >> 10;
    const float* adjrow = adj + (size_t)bn * 1024;
    const float* krow = kv + (b << 10);
    float q = qv[bn];
    int m0 = threadIdx.x * 4;

    float4 a4 = *reinterpret_cast<const float4*>(adjrow + m0);
    float4 k4 = *reinterpret_cast<const float4*>(krow + m0);
    float v[4];
    v[0] = q + k4.x + (1.f - a4.x) * -1.0e9f;
    v[1] = q + k4.y + (1.f - a4.y) * -1.0e9f;
    v[2] = q + k4.z + (1.f - a4.z) * -1.0e9f;
    v[3] = q + k4.w + (1.f - a4.w) * -1.0e9f;
#pragma unroll
    for (int t = 0; t < 4; t++) v[t] = v[t] >= 0.f ? v[t] : 0.01f * v[t];

    float mx = fmaxf(fmaxf(v[0], v[1]), fmaxf(v[2], v[3]));
    __shared__ float red[4];
#pragma unroll
    for (int off = 32; off; off >>= 1) mx = fmaxf(mx, __shfl_xor(mx, off));
    if ((threadIdx.x & 63) == 0) red[threadIdx.x >> 6] = mx;
    __syncthreads();
    mx = fmaxf(fmaxf(red[0], red[1]), fmaxf(red[2], red[3]));

    float s = 0.f;
#pragma unroll
    for (int t = 0; t < 4; t++) { v[t] = __expf(v[t] - mx); s += v[t]; }
#pragma unroll
    for (int off = 32; off; off >>= 1) s += __shfl_xor(s, off);
    __syncthreads();
    if ((threadIdx.x & 63) == 0) red[threadIdx.x >> 6] = s;
    __syncthreads();
    s = red[0] + red[1] + red[2] + red[3];
    float inv = 1.f / s;

    us4 o;
    o.x = f2bf(v[0] * inv); o.y = f2bf(v[1] * inv);
    o.z = f2bf(v[2] * inv); o.w = f2bf(v[3] * inv);
    *reinterpret_cast<us4*>(attb + (size_t)bn * 1024 + m0) = o;
}

extern "C" void kernel_launch(void* const* d_in, const int* in_sizes, int n_in,
                              void* d_out, int out_size, void* d_ws, size_t ws_size,
                              hipStream_t stream) {
    const float* x    = (const float*)d_in[0];
    const float* adj  = (const float*)d_in[1];
    const float* W_fc = (const float*)d_in[2];
    const float* b_fc = (const float*)d_in[3];
    const float* w_q  = (const float*)d_in[4];
    const float* b_q  = (const float*)d_in[5];
    const float* w_k  = (const float*)d_in[6];
    const float* b_k  = (const float*)d_in[7];
    const float* W_uy = (const float*)d_in[8];
    const float* b_uy = (const float*)d_in[9];
    const float* W_ux = (const float*)d_in[10];
    const float* b_ux = (const float*)d_in[11];
    const float* W_ry = (const float*)d_in[12];
    const float* b_ry = (const float*)d_in[13];
    const float* W_rx = (const float*)d_in[14];
    const float* b_rx = (const float*)d_in[15];
    const float* W_ty = (const float*)d_in[16];
    const float* b_ty = (const float*)d_in[17];
    const float* W_tx = (const float*)d_in[18];
    const float* b_tx = (const float*)d_in[19];

    char* ws = (char*)d_ws;
    // workspace layout (bytes), total 200 MiB
    u16*   Xb    = (u16*)  (ws + 0);            // 16384x768 bf16      = 25165824
    u16*   Wb    = (u16*)  (ws + 25165824);     // 7 x 768x768 bf16    =  8257536
    u16*   fpT   = (u16*)  (ws + 33423360);     // 16x768x1024 bf16    = 25165824
    float* qv    = (float*)(ws + 58589184);     // 16384 f32
    float* kv    = (float*)(ws + 58654720);     // 16384 f32
    u16*   attb  = (u16*)  (ws + 58720256);     // 16x1024x1024 bf16   = 33554432
    float* u_ws  = (float*)(ws + 58720256);     // aliases attb (att dead after k_av)
    u16*   yb    = (u16*)  (ws + 109051904);    // 16384x768 bf16      = 25165824
    float* ty_ws = (float*)(ws + 134217728);    // 16384x768 f32       = 50331648
    u16*   rxb   = (u16*)  (ws + 184549376);    // 16384x768 bf16      = 25165824

    u16* Wfc_b = Wb + 0 * 589824;
    u16* Wuy_b = Wb + 1 * 589824;
    u16* Wux_b = Wb + 2 * 589824;
    u16* Wry_b = Wb + 3 * 589824;
    u16* Wrx_b = Wb + 4 * 589824;
    u16* Wty_b = Wb + 5 * 589824;
    u16* Wtx_b = Wb + 6 * 589824;

    cvt4<<<12288, 256, 0, stream>>>(x, Xb, 3145728);
    cvt4<<<576, 256, 0, stream>>>(W_fc, Wfc_b, 147456);
    cvt4<<<576, 256, 0, stream>>>(W_uy, Wuy_b, 147456);
    cvt4<<<576, 256, 0, stream>>>(W_ux, Wux_b, 147456);
    cvt4<<<576, 256, 0, stream>>>(W_ry, Wry_b, 147456);
    cvt4<<<576, 256, 0, stream>>>(W_rx, Wrx_b, 147456);
    cvt4<<<576, 256, 0, stream>>>(W_ty, Wty_b, 147456);
    cvt4<<<576, 256, 0, stream>>>(W_tx, Wtx_b, 147456);

    Epi e{};

    // feat_proj = X @ Wfc^T + b, stored transposed fpT[b][d][n]
    e = Epi{}; e.b1 = b_fc; e.fpT = fpT;
    g128<EPI_FPT, 1><<<dim3(128, 6), 256, 0, stream>>>(Xb, Wfc_b, nullptr, nullptr,
                                                       768, 768, 768, 0, 0, 0, e);
    k_qk<<<64, 256, 0, stream>>>(fpT, w_q, b_q, w_k, b_k, qv, kv);
    k_soft<<<16384, 256, 0, stream>>>(adj, qv, kv, attb);

    // y = att @ fp  (batched; fpT serves as B^T with ldB=1024)
    e = Epi{}; e.ob = yb;
    g128<EPI_Y, 1><<<dim3(8, 6, 16), 256, 0, stream>>>(attb, fpT, nullptr, nullptr,
                                                       1024, 1024, 1024,
                                                       1048576, 786432, 1024, e);
    // u = sigmoid(y@Wuy^T + x@Wux^T + b)   (writes over dead attb)
    e = Epi{}; e.b1 = b_uy; e.b2 = b_ux; e.of = u_ws;
    g128<EPI_U, 2><<<dim3(128, 6), 256, 0, stream>>>(yb, Wuy_b, Xb, Wux_b,
                                                     768, 768, 768, 0, 0, 0, e);
    // rx = sigmoid(y@Wry^T + x@Wrx^T + b) * x
    e = Epi{}; e.b1 = b_ry; e.b2 = b_rx; e.xin = x; e.ob = rxb;
    g128<EPI_RX, 2><<<dim3(128, 6), 256, 0, stream>>>(yb, Wry_b, Xb, Wrx_b,
                                                      768, 768, 768, 0, 0, 0, e);
    // ty = y@Wty^T + b
    e = Epi{}; e.b1 = b_ty; e.of = ty_ws;
    g128<EPI_T, 1><<<dim3(128, 6), 256, 0, stream>>>(yb, Wty_b, nullptr, nullptr,
                                                     768, 768, 768, 0, 0, 0, e);
    // out = (1-u)x + u*tanh(ty + rx@Wtx^T + b)
    e = Epi{}; e.b1 = b_tx; e.xin = x; e.ty = ty_ws; e.u = u_ws; e.of = (float*)d_out;
    g128<EPI_OUT, 1><<<dim3(128, 6), 256, 0, stream>>>(rxb, Wtx_b, nullptr, nullptr,
                                                       768, 768, 768, 0, 0, 0, e);
}

// Round 3
// 475.703 us; speedup vs baseline: 2.1686x; 1.2097x over previous
//
#include <hip/hip_runtime.h>
#include <cmath>

typedef __attribute__((ext_vector_type(8))) short bf16x8;
typedef __attribute__((ext_vector_type(4))) float f32x4;
typedef unsigned short u16;

struct __align__(8) us4 { u16 x, y, z, w; };

__device__ __forceinline__ u16 f2bf(float f) {
    union { float f; unsigned u; } v; v.f = f;
    unsigned u = v.u;
    u += 0x7fffu + ((u >> 16) & 1u);   // RNE
    return (u16)(u >> 16);
}
__device__ __forceinline__ float bf2f(u16 h) {
    union { unsigned u; float f; } v; v.u = ((unsigned)h) << 16;
    return v.f;
}
__device__ __forceinline__ f32x4 mfma16(bf16x8 a, bf16x8 b, f32x4 c) {
    return __builtin_amdgcn_mfma_f32_16x16x32_bf16(a, b, c, 0, 0, 0);
}
__device__ __forceinline__ void ld_lds16(const u16* g, u16* l) {
    __builtin_amdgcn_global_load_lds(
        (const __attribute__((address_space(1))) unsigned int*)g,
        (__attribute__((address_space(3))) unsigned int*)l, 16, 0, 0);
}

// ---------------- zero q/k accumulators ----------------
__global__ __launch_bounds__(256) void zqk(float* qv, float* kv) {
    int i = blockIdx.x * 256 + threadIdx.x;
    qv[i] = 0.f; kv[i] = 0.f;
}

// ---------------- x -> bf16 (Xb) + CatA right half ----------------
__global__ __launch_bounds__(256) void cvtx(const float* __restrict__ in,
                                            u16* __restrict__ Xb, u16* __restrict__ CatA) {
    int i = blockIdx.x * 256 + threadIdx.x;         // over 3145728 float4 groups
    float4 f = reinterpret_cast<const float4*>(in)[i];
    us4 o; o.x = f2bf(f.x); o.y = f2bf(f.y); o.z = f2bf(f.z); o.w = f2bf(f.w);
    reinterpret_cast<us4*>(Xb)[i] = o;
    int fe = i * 4, row = fe / 768, col = fe % 768;
    *reinterpret_cast<us4*>(CatA + (size_t)row * 1536 + 768 + col) = o;
}

// ---------------- 8 weight converts in one dispatch ----------------
struct WCvt { const float* s[8]; u16* d[8]; int ld[8]; };
__global__ __launch_bounds__(256) void cvtw(WCvt w) {
    int wi = blockIdx.y;
    int i = blockIdx.x * 256 + threadIdx.x;         // over 147456 float4 groups
    float4 f = reinterpret_cast<const float4*>(w.s[wi])[i];
    us4 o; o.x = f2bf(f.x); o.y = f2bf(f.y); o.z = f2bf(f.z); o.w = f2bf(f.w);
    int fe = i * 4, row = fe / 768, col = fe % 768;
    *reinterpret_cast<us4*>(w.d[wi] + (size_t)row * w.ld[wi] + col) = o;
}

// =====================================================================
// m97-style GEMM, 128x128 tile, BK=32, global_load_lds w16, XOR-swizzled
// LDS k-chunks (swizzle applied on global address; lane->LDS slot fixed).
// =====================================================================
enum { EPI_FPT = 0, EPI_Y, EPI_GATES, EPI_OUT };

struct Epi {
    const float* b_fc; const float* wq; const float* wk; float* qv; float* kv;  // FPT
    u16* fpT;
    u16* catA;                                                                   // Y out
    const float* b_uy; const float* b_ux; const float* b_ry; const float* b_rx;  // GATES
    const float* b_ty;
    const u16* xb; u16* ub_o; u16* tyb_o; u16* rxb_o;
    const float* btx; const u16* tyb; const u16* ub; float* of;                  // OUT
};

template<int EPI>
__global__ __launch_bounds__(256) void g128(
    const u16* __restrict__ A, const u16* __restrict__ Bm,
    int K, int ldA, int ldB, size_t zA, size_t zB, Epi e)
{
    __shared__ u16 lA[128 * 32];
    __shared__ u16 lB[128 * 32];

    const int t = threadIdx.x;
    const int w = t >> 6, lane = t & 63, lm = lane & 15, quad = lane >> 4;
    const int row0 = blockIdx.x * 128, col0 = blockIdx.y * 128;

    if constexpr (EPI == EPI_GATES) { if (blockIdx.y >= 12) K = 768; }

    // staging: lane covers (rs, chunk t&3); global chunk XOR-swizzled by (rs>>1)&3
    const int rs = t >> 2;
    const int kc = ((t & 3) * 8) ^ ((((rs >> 1) & 3)) << 3);
    u16* dA0 = lA + w * 512;
    u16* dA1 = lA + 2048 + w * 512;
    u16* dB0 = lB + w * 512;
    u16* dB1 = lB + 2048 + w * 512;

    const u16* As = A + (size_t)blockIdx.z * zA;
    const u16* Bs = Bm + (size_t)blockIdx.z * zB;
    const u16* gA0 = As + (size_t)(row0 + rs) * ldA + kc;
    const u16* gA1 = As + (size_t)(row0 + 64 + rs) * ldA + kc;
    const u16* gB0 = Bs + (size_t)(col0 + rs) * ldB + kc;
    const u16* gB1 = Bs + (size_t)(col0 + 64 + rs) * ldB + kc;

    // compute map: wave (w&1) row-half, (w>>1) col-half; swizzle term (lm>>1)&3
    const int rw0 = (w & 1) * 64, cw0 = (w >> 1) * 64;
    const int sw = (lm >> 1) & 3;
    const u16* la[4]; const u16* lb[4];
#pragma unroll
    for (int i = 0; i < 4; i++) la[i] = lA + (rw0 + i * 16 + lm) * 32 + ((quad ^ sw) * 8);
#pragma unroll
    for (int j = 0; j < 4; j++) lb[j] = lB + (cw0 + j * 16 + lm) * 32 + ((quad ^ sw) * 8);

    f32x4 acc[4][4] = {};

    for (int k0 = 0; k0 < K; k0 += 32) {
        if (k0 != 0) __syncthreads();
        ld_lds16(gA0 + k0, dA0);
        ld_lds16(gA1 + k0, dA1);
        ld_lds16(gB0 + k0, dB0);
        ld_lds16(gB1 + k0, dB1);
        __syncthreads();

        bf16x8 a[4], b[4];
#pragma unroll
        for (int i = 0; i < 4; i++) a[i] = *reinterpret_cast<const bf16x8*>(la[i]);
#pragma unroll
        for (int j = 0; j < 4; j++) b[j] = *reinterpret_cast<const bf16x8*>(lb[j]);
#pragma unroll
        for (int i = 0; i < 4; i++)
#pragma unroll
            for (int j = 0; j < 4; j++)
                acc[i][j] = mfma16(a[i], b[j], acc[i][j]);
    }

    // ---------------- epilogue ----------------
#pragma unroll
    for (int i = 0; i < 4; i++) {
        const int gr = row0 + rw0 + i * 16 + quad * 4;   // local (per-z) row
        if constexpr (EPI == EPI_FPT) {
            float qp[4] = {}, kp[4] = {};
            int bb = gr >> 10, nn = gr & 1023;
#pragma unroll
            for (int j = 0; j < 4; j++) {
                int gc = col0 + cw0 + j * 16 + lm;
                float bias = e.b_fc[gc];
                float v0 = acc[i][j][0] + bias, v1 = acc[i][j][1] + bias;
                float v2 = acc[i][j][2] + bias, v3 = acc[i][j][3] + bias;
                us4 o; o.x = f2bf(v0); o.y = f2bf(v1); o.z = f2bf(v2); o.w = f2bf(v3);
                *reinterpret_cast<us4*>(e.fpT + (size_t)bb * 786432 + (size_t)gc * 1024 + nn) = o;
                float wqv = e.wq[gc], wkv = e.wk[gc];
                qp[0] = fmaf(v0, wqv, qp[0]); qp[1] = fmaf(v1, wqv, qp[1]);
                qp[2] = fmaf(v2, wqv, qp[2]); qp[3] = fmaf(v3, wqv, qp[3]);
                kp[0] = fmaf(v0, wkv, kp[0]); kp[1] = fmaf(v1, wkv, kp[1]);
                kp[2] = fmaf(v2, wkv, kp[2]); kp[3] = fmaf(v3, wkv, kp[3]);
            }
#pragma unroll
            for (int r = 0; r < 4; r++) {
                float q = qp[r], k = kp[r];
#pragma unroll
                for (int m = 1; m < 16; m <<= 1) { q += __shfl_xor(q, m); k += __shfl_xor(k, m); }
                if (lm == 0) { atomicAdd(e.qv + gr + r, q); atomicAdd(e.kv + gr + r, k); }
            }
        } else if constexpr (EPI == EPI_Y) {
            size_t grow = (size_t)blockIdx.z * 1024 + gr;
#pragma unroll
            for (int j = 0; j < 4; j++) {
                int gc = col0 + cw0 + j * 16 + lm;
#pragma unroll
                for (int r = 0; r < 4; r++)
                    e.catA[(grow + r) * 1536 + gc] = f2bf(acc[i][j][r]);
            }
        } else if constexpr (EPI == EPI_GATES) {
            int grp = blockIdx.y / 6;
            int oc0 = (blockIdx.y % 6) * 128 + cw0;
#pragma unroll
            for (int j = 0; j < 4; j++) {
                int gc = oc0 + j * 16 + lm;
                if (grp == 0) {
                    float bias = e.b_uy[gc] + e.b_ux[gc];
#pragma unroll
                    for (int r = 0; r < 4; r++) {
                        size_t idx = (size_t)(gr + r) * 768 + gc;
                        e.ub_o[idx] = f2bf(1.f / (1.f + __expf(-(acc[i][j][r] + bias))));
                    }
                } else if (grp == 1) {
                    float bias = e.b_ry[gc] + e.b_rx[gc];
#pragma unroll
                    for (int r = 0; r < 4; r++) {
                        size_t idx = (size_t)(gr + r) * 768 + gc;
                        float rr = 1.f / (1.f + __expf(-(acc[i][j][r] + bias)));
                        e.rxb_o[idx] = f2bf(rr * bf2f(e.xb[idx]));
                    }
                } else {
                    float bias = e.b_ty[gc];
#pragma unroll
                    for (int r = 0; r < 4; r++) {
                        size_t idx = (size_t)(gr + r) * 768 + gc;
                        e.tyb_o[idx] = f2bf(acc[i][j][r] + bias);
                    }
                }
            }
        } else {  // EPI_OUT
#pragma unroll
            for (int j = 0; j < 4; j++) {
                int gc = col0 + cw0 + j * 16 + lm;
                float bias = e.btx[gc];
#pragma unroll
                for (int r = 0; r < 4; r++) {
                    size_t idx = (size_t)(gr + r) * 768 + gc;
                    float tt = tanhf(acc[i][j][r] + bias + bf2f(e.tyb[idx]));
                    float uu = bf2f(e.ub[idx]);
                    float xv = bf2f(e.xb[idx]);
                    e.of[idx] = (1.f - uu) * xv + uu * tt;
                }
            }
        }
    }
}

// ---------------- masked leaky-relu softmax rows -> att (bf16) ----------------
__global__ __launch_bounds__(256) void k_soft(const float* __restrict__ adj,
                                              const float* __restrict__ qv,
                                              const float* __restrict__ kv,
                                              const float* __restrict__ bq,
                                              const float* __restrict__ bk,
                                              u16* __restrict__ attb) {
    int bn = blockIdx.x;
    int b = bn >> 10;
    const float* adjrow = adj + (size_t)bn * 1024;
    const float* krow = kv + (b << 10);
    float q = qv[bn] + bq[0] + bk[0];
    int m0 = threadIdx.x * 4;

    float4 a4 = *reinterpret_cast<const float4*>(adjrow + m0);
    float4 k4 = *reinterpret_cast<const float4*>(krow + m0);
    float v[4];
    v[0] = q + k4.x + (1.f - a4.x) * -1.0e9f;
    v[1] = q + k4.y + (1.f - a4.y) * -1.0e9f;
    v[2] = q + k4.z + (1.f - a4.z) * -1.0e9f;
    v[3] = q + k4.w + (1.f - a4.w) * -1.0e9f;
#pragma unroll
    for (int t = 0; t < 4; t++) v[t] = v[t] >= 0.f ? v[t] : 0.01f * v[t];

    float mx = fmaxf(fmaxf(v[0], v[1]), fmaxf(v[2], v[3]));
    __shared__ float red[4];
#pragma unroll
    for (int off = 32; off; off >>= 1) mx = fmaxf(mx, __shfl_xor(mx, off));
    if ((threadIdx.x & 63) == 0) red[threadIdx.x >> 6] = mx;
    __syncthreads();
    mx = fmaxf(fmaxf(red[0], red[1]), fmaxf(red[2], red[3]));

    float s = 0.f;
#pragma unroll
    for (int t = 0; t < 4; t++) { v[t] = __expf(v[t] - mx); s += v[t]; }
#pragma unroll
    for (int off = 32; off; off >>= 1) s += __shfl_xor(s, off);
    __syncthreads();
    if ((threadIdx.x & 63) == 0) red[threadIdx.x >> 6] = s;
    __syncthreads();
    s = red[0] + red[1] + red[2] + red[3];
    float inv = 1.f / s;

    us4 o;
    o.x = f2bf(v[0] * inv); o.y = f2bf(v[1] * inv);
    o.z = f2bf(v[2] * inv); o.w = f2bf(v[3] * inv);
    *reinterpret_cast<us4*>(attb + (size_t)bn * 1024 + m0) = o;
}

extern "C" void kernel_launch(void* const* d_in, const int* in_sizes, int n_in,
                              void* d_out, int out_size, void* d_ws, size_t ws_size,
                              hipStream_t stream) {
    const float* x    = (const float*)d_in[0];
    const float* adj  = (const float*)d_in[1];
    const float* W_fc = (const float*)d_in[2];
    const float* b_fc = (const float*)d_in[3];
    const float* w_q  = (const float*)d_in[4];
    const float* b_q  = (const float*)d_in[5];
    const float* w_k  = (const float*)d_in[6];
    const float* b_k  = (const float*)d_in[7];
    const float* W_uy = (const float*)d_in[8];
    const float* b_uy = (const float*)d_in[9];
    const float* W_ux = (const float*)d_in[10];
    const float* b_ux = (const float*)d_in[11];
    const float* W_ry = (const float*)d_in[12];
    const float* b_ry = (const float*)d_in[13];
    const float* W_rx = (const float*)d_in[14];
    const float* b_rx = (const float*)d_in[15];
    const float* W_ty = (const float*)d_in[16];
    const float* b_ty = (const float*)d_in[17];
    const float* W_tx = (const float*)d_in[18];
    const float* b_tx = (const float*)d_in[19];

    char* ws = (char*)d_ws;
    u16*   Xb    = (u16*)  (ws + 0);            // 16384x768 bf16        25165824
    u16*   Wfc_b = (u16*)  (ws + 25165824);     // 768x768 bf16           1179648
    u16*   Wtx_b = (u16*)  (ws + 26345472);     // 768x768 bf16           1179648
    u16*   Wg    = (u16*)  (ws + 27525120);     // 2304x1536 bf16         7077888
    u16*   fpT   = (u16*)  (ws + 34603008);     // 16x768x1024 bf16      25165824
    float* qv    = (float*)(ws + 59768832);     // 16384 f32
    float* kv    = (float*)(ws + 59834368);     // 16384 f32
    u16*   attb  = (u16*)  (ws + 59899904);     // 16x1024x1024 bf16     33554432  (dead after g_av)
    u16*   u_b   = (u16*)  (ws + 59899904);     // alias attb            25165824
    u16*   CatA  = (u16*)  (ws + 93454336);     // 16384x1536 bf16       50331648
    u16*   ty_b  = (u16*)  (ws + 143785984);    // 16384x768 bf16        25165824
    u16*   rxb   = (u16*)  (ws + 168951808);    // 16384x768 bf16        25165824

    zqk<<<64, 256, 0, stream>>>(qv, kv);
    cvtx<<<12288, 256, 0, stream>>>(x, Xb, CatA);

    WCvt wc;
    wc.s[0] = W_fc; wc.d[0] = Wfc_b;            wc.ld[0] = 768;
    wc.s[1] = W_tx; wc.d[1] = Wtx_b;            wc.ld[1] = 768;
    wc.s[2] = W_uy; wc.d[2] = Wg;               wc.ld[2] = 1536;
    wc.s[3] = W_ux; wc.d[3] = Wg + 768;         wc.ld[3] = 1536;
    wc.s[4] = W_ry; wc.d[4] = Wg + 768*1536;    wc.ld[4] = 1536;
    wc.s[5] = W_rx; wc.d[5] = Wg + 768*1536+768;wc.ld[5] = 1536;
    wc.s[6] = W_ty; wc.d[6] = Wg + 1536*1536;   wc.ld[6] = 1536;
    wc.s[7] = W_ty; wc.d[7] = Wg + 1536*1536+768; wc.ld[7] = 1536;  // junk fill, never read
    cvtw<<<dim3(576, 8), 256, 0, stream>>>(wc);

    Epi e{};
    // feat_proj (+ fused q/k partials)
    e = Epi{}; e.b_fc = b_fc; e.wq = w_q; e.wk = w_k; e.qv = qv; e.kv = kv; e.fpT = fpT;
    g128<EPI_FPT><<<dim3(128, 6), 256, 0, stream>>>(Xb, Wfc_b, 768, 768, 768, 0, 0, e);

    k_soft<<<16384, 256, 0, stream>>>(adj, qv, kv, b_q, b_k, attb);

    // y = att @ fp  -> CatA left half
    e = Epi{}; e.catA = CatA;
    g128<EPI_Y><<<dim3(8, 6, 16), 256, 0, stream>>>(attb, fpT, 1024, 1024, 1024,
                                                    1048576, 786432, e);
    // merged gates: [u | r | ty] = CatA @ Wg^T
    e = Epi{}; e.b_uy = b_uy; e.b_ux = b_ux; e.b_ry = b_ry; e.b_rx = b_rx; e.b_ty = b_ty;
    e.xb = Xb; e.ub_o = u_b; e.tyb_o = ty_b; e.rxb_o = rxb;
    g128<EPI_GATES><<<dim3(128, 18), 256, 0, stream>>>(CatA, Wg, 1536, 1536, 1536, 0, 0, e);

    // out = (1-u)x + u*tanh(ty + rx@Wtx^T + b)
    e = Epi{}; e.btx = b_tx; e.tyb = ty_b; e.ub = u_b; e.xb = Xb; e.of = (float*)d_out;
    g128<EPI_OUT><<<dim3(128, 6), 256, 0, stream>>>(rxb, Wtx_b, 768, 768, 768, 0, 0, e);
}

// Round 4
// 462.786 us; speedup vs baseline: 2.2291x; 1.0279x over previous
//
#include <hip/hip_runtime.h>
#include <cmath>

typedef __attribute__((ext_vector_type(8))) short bf16x8;
typedef __attribute__((ext_vector_type(4))) float f32x4;
typedef unsigned short u16;

struct __align__(8) us4 { u16 x, y, z, w; };

__device__ __forceinline__ u16 f2bf(float f) {
    union { float f; unsigned u; } v; v.f = f;
    unsigned u = v.u;
    u += 0x7fffu + ((u >> 16) & 1u);   // RNE
    return (u16)(u >> 16);
}
__device__ __forceinline__ float bf2f(u16 h) {
    union { unsigned u; float f; } v; v.u = ((unsigned)h) << 16;
    return v.f;
}
__device__ __forceinline__ f32x4 mfma16(bf16x8 a, bf16x8 b, f32x4 c) {
    return __builtin_amdgcn_mfma_f32_16x16x32_bf16(a, b, c, 0, 0, 0);
}
__device__ __forceinline__ void ld_lds16(const u16* g, u16* l) {
    __builtin_amdgcn_global_load_lds(
        (const __attribute__((address_space(1))) unsigned int*)g,
        (__attribute__((address_space(3))) unsigned int*)l, 16, 0, 0);
}

// ---------------- x -> CatA right half (bf16) + zero qv/kv ----------------
__global__ __launch_bounds__(256) void cvtx(const float* __restrict__ in,
                                            u16* __restrict__ CatA, float* __restrict__ qkz) {
    int i = blockIdx.x * 256 + threadIdx.x;         // over 3145728 float4 groups
    float4 f = reinterpret_cast<const float4*>(in)[i];
    us4 o; o.x = f2bf(f.x); o.y = f2bf(f.y); o.z = f2bf(f.z); o.w = f2bf(f.w);
    int row = i / 192, col = (i % 192) * 4;
    *reinterpret_cast<us4*>(CatA + (size_t)row * 1536 + 768 + col) = o;
    if (i < 8192) reinterpret_cast<float4*>(qkz)[i] = float4{0.f, 0.f, 0.f, 0.f};
}

// ---------------- 7 weight converts in one dispatch ----------------
struct WCvt { const float* s[7]; u16* d[7]; int ld[7]; };
__global__ __launch_bounds__(256) void cvtw(WCvt w) {
    int wi = blockIdx.y;
    int i = blockIdx.x * 256 + threadIdx.x;         // over 147456 float4 groups
    float4 f = reinterpret_cast<const float4*>(w.s[wi])[i];
    us4 o; o.x = f2bf(f.x); o.y = f2bf(f.y); o.z = f2bf(f.z); o.w = f2bf(f.w);
    int row = i / 192, col = (i % 192) * 4;
    *reinterpret_cast<us4*>(w.d[wi] + (size_t)row * w.ld[wi] + col) = o;
}

// =====================================================================
// m97-style GEMM, 128x128 tile, BK=32, global_load_lds w16, XOR-swizzled
// k-chunks (0 bank conflicts — verified round 3). Optional 2nd phase
// accumulates A2 @ B2^T into the same accumulators.
// =====================================================================
enum { EPI_FPT = 0, EPI_Y, EPI_GATES, EPI_OUT };

struct Epi {
    const float* b1; const float* b2; const float* b3; const float* b4;
    const float* wq; const float* wk; float* qv; float* kv;   // FPT
    u16* fpT;
    u16* catA;                                                 // Y
    const u16* xb;        // CatA+768 (stride 1536)
    u16* ub_o; u16* rxb_o;                                     // GATES
    const u16* ub; float* of;                                  // OUT
};

template<int EPI, int PH>
__global__ __launch_bounds__(256) void g128(
    const u16* __restrict__ A1, const u16* __restrict__ B1,
    const u16* __restrict__ A2, const u16* __restrict__ B2,
    int K, int ldA1, int ldB1, int ldA2, int ldB2,
    size_t zA, size_t zB, Epi e)
{
    __shared__ u16 lA[128 * 32];
    __shared__ u16 lB[128 * 32];

    const int t = threadIdx.x;
    const int w = t >> 6, lane = t & 63, lm = lane & 15, quad = lane >> 4;
    const int row0 = blockIdx.x * 128;
    int col0, grp = 0;
    if constexpr (EPI == EPI_GATES) { grp = blockIdx.y / 6; col0 = (blockIdx.y % 6) * 128; }
    else col0 = blockIdx.y * 128;

    // staging: lane covers (rs, chunk t&3); global chunk XOR-swizzled by (rs>>1)&3
    const int rs = t >> 2;
    const int kc = ((t & 3) * 8) ^ ((((rs >> 1) & 3)) << 3);
    u16* dA0 = lA + w * 512;
    u16* dA1p = lA + 2048 + w * 512;
    u16* dB0 = lB + w * 512;
    u16* dB1p = lB + 2048 + w * 512;

    // compute map: wave (w&1) row-half, (w>>1) col-half; matching un-swizzle
    const int rw0 = (w & 1) * 64, cw0 = (w >> 1) * 64;
    const int sw = (lm >> 1) & 3;
    const u16* la[4]; const u16* lb[4];
#pragma unroll
    for (int i = 0; i < 4; i++) la[i] = lA + (rw0 + i * 16 + lm) * 32 + ((quad ^ sw) * 8);
#pragma unroll
    for (int j = 0; j < 4; j++) lb[j] = lB + (cw0 + j * 16 + lm) * 32 + ((quad ^ sw) * 8);

    f32x4 acc[4][4] = {};
    bool first = true;

#pragma unroll
    for (int ph = 0; ph < PH; ph++) {
        const u16* As; const u16* Bs; int ldA, ldB;
        if (ph == 0) { As = A1 + (size_t)blockIdx.z * zA; Bs = B1 + (size_t)blockIdx.z * zB; ldA = ldA1; ldB = ldB1; }
        else         { As = A2; Bs = B2; ldA = ldA2; ldB = ldB2; }
        if constexpr (EPI == EPI_GATES) Bs += (size_t)grp * (768 * 1536);
        const u16* gA0 = As + (size_t)(row0 + rs) * ldA + kc;
        const u16* gA1 = As + (size_t)(row0 + 64 + rs) * ldA + kc;
        const u16* gB0 = Bs + (size_t)(col0 + rs) * ldB + kc;
        const u16* gB1 = Bs + (size_t)(col0 + 64 + rs) * ldB + kc;

        for (int k0 = 0; k0 < K; k0 += 32) {
            if (!first) __syncthreads();
            first = false;
            ld_lds16(gA0 + k0, dA0);
            ld_lds16(gA1 + k0, dA1p);
            ld_lds16(gB0 + k0, dB0);
            ld_lds16(gB1 + k0, dB1p);
            __syncthreads();

            bf16x8 a[4], b[4];
#pragma unroll
            for (int i = 0; i < 4; i++) a[i] = *reinterpret_cast<const bf16x8*>(la[i]);
#pragma unroll
            for (int j = 0; j < 4; j++) b[j] = *reinterpret_cast<const bf16x8*>(lb[j]);
#pragma unroll
            for (int i = 0; i < 4; i++)
#pragma unroll
                for (int j = 0; j < 4; j++)
                    acc[i][j] = mfma16(a[i], b[j], acc[i][j]);
        }
    }

    // ---------------- epilogue ----------------
#pragma unroll
    for (int i = 0; i < 4; i++) {
        const int gr = row0 + rw0 + i * 16 + quad * 4;   // local (per-z) row
        if constexpr (EPI == EPI_FPT) {
            float qp[4] = {}, kp[4] = {};
            int bb = gr >> 10, nn = gr & 1023;
#pragma unroll
            for (int j = 0; j < 4; j++) {
                int gc = col0 + cw0 + j * 16 + lm;
                float bias = e.b1[gc];
                float v0 = acc[i][j][0] + bias, v1 = acc[i][j][1] + bias;
                float v2 = acc[i][j][2] + bias, v3 = acc[i][j][3] + bias;
                us4 o; o.x = f2bf(v0); o.y = f2bf(v1); o.z = f2bf(v2); o.w = f2bf(v3);
                *reinterpret_cast<us4*>(e.fpT + (size_t)bb * 786432 + (size_t)gc * 1024 + nn) = o;
                float wqv = e.wq[gc], wkv = e.wk[gc];
                qp[0] = fmaf(v0, wqv, qp[0]); qp[1] = fmaf(v1, wqv, qp[1]);
                qp[2] = fmaf(v2, wqv, qp[2]); qp[3] = fmaf(v3, wqv, qp[3]);
                kp[0] = fmaf(v0, wkv, kp[0]); kp[1] = fmaf(v1, wkv, kp[1]);
                kp[2] = fmaf(v2, wkv, kp[2]); kp[3] = fmaf(v3, wkv, kp[3]);
            }
#pragma unroll
            for (int r = 0; r < 4; r++) {
                float q = qp[r], k = kp[r];
#pragma unroll
                for (int m = 1; m < 16; m <<= 1) { q += __shfl_xor(q, m); k += __shfl_xor(k, m); }
                if (lm == 0) { atomicAdd(e.qv + gr + r, q); atomicAdd(e.kv + gr + r, k); }
            }
        } else if constexpr (EPI == EPI_Y) {
            size_t grow = (size_t)blockIdx.z * 1024 + gr;
#pragma unroll
            for (int j = 0; j < 4; j++) {
                int gc = col0 + cw0 + j * 16 + lm;
#pragma unroll
                for (int r = 0; r < 4; r++)
                    e.catA[(grow + r) * 1536 + gc] = f2bf(acc[i][j][r]);
            }
        } else if constexpr (EPI == EPI_GATES) {
#pragma unroll
            for (int j = 0; j < 4; j++) {
                int gc = col0 + cw0 + j * 16 + lm;
                if (grp == 0) {
                    float bias = e.b1[gc] + e.b2[gc];      // b_uy + b_ux
#pragma unroll
                    for (int r = 0; r < 4; r++) {
                        size_t idx = (size_t)(gr + r) * 768 + gc;
                        e.ub_o[idx] = f2bf(1.f / (1.f + __expf(-(acc[i][j][r] + bias))));
                    }
                } else {
                    float bias = e.b3[gc] + e.b4[gc];      // b_ry + b_rx
#pragma unroll
                    for (int r = 0; r < 4; r++) {
                        size_t idx = (size_t)(gr + r) * 768 + gc;
                        float rr = 1.f / (1.f + __expf(-(acc[i][j][r] + bias)));
                        float xv = bf2f(e.xb[(size_t)(gr + r) * 1536 + gc]);
                        e.rxb_o[idx] = f2bf(rr * xv);
                    }
                }
            }
        } else {  // EPI_OUT: acc = y@Wty + rx@Wtx
#pragma unroll
            for (int j = 0; j < 4; j++) {
                int gc = col0 + cw0 + j * 16 + lm;
                float bias = e.b1[gc] + e.b2[gc];          // b_ty + b_tx
#pragma unroll
                for (int r = 0; r < 4; r++) {
                    size_t idx = (size_t)(gr + r) * 768 + gc;
                    float tt = tanhf(acc[i][j][r] + bias);
                    float uu = bf2f(e.ub[idx]);
                    float xv = bf2f(e.xb[(size_t)(gr + r) * 1536 + gc]);
                    e.of[idx] = (1.f - uu) * xv + uu * tt;
                }
            }
        }
    }
}

// ---------------- softmax: one wave per row, shuffle-only reductions ----------------
__global__ __launch_bounds__(256) void k_soft4(const float* __restrict__ adj,
                                               const float* __restrict__ qv,
                                               const float* __restrict__ kv,
                                               const float* __restrict__ bq,
                                               const float* __restrict__ bk,
                                               u16* __restrict__ attb) {
    int wv = threadIdx.x >> 6, lane = threadIdx.x & 63;
    int bn = blockIdx.x * 4 + wv;
    int b = bn >> 10;
    const float* adjrow = adj + (size_t)bn * 1024 + lane * 16;
    const float* krow = kv + (b << 10) + lane * 16;
    float q = qv[bn] + bq[0] + bk[0];

    float v[16];
#pragma unroll
    for (int c = 0; c < 4; c++) {
        float4 a4 = *reinterpret_cast<const float4*>(adjrow + c * 4);
        float4 k4 = *reinterpret_cast<const float4*>(krow + c * 4);
        float* vv = v + c * 4;
        vv[0] = q + k4.x + (1.f - a4.x) * -1.0e9f;
        vv[1] = q + k4.y + (1.f - a4.y) * -1.0e9f;
        vv[2] = q + k4.z + (1.f - a4.z) * -1.0e9f;
        vv[3] = q + k4.w + (1.f - a4.w) * -1.0e9f;
    }
#pragma unroll
    for (int t = 0; t < 16; t++) v[t] = v[t] >= 0.f ? v[t] : 0.01f * v[t];

    float mx = v[0];
#pragma unroll
    for (int t = 1; t < 16; t++) mx = fmaxf(mx, v[t]);
#pragma unroll
    for (int off = 32; off; off >>= 1) mx = fmaxf(mx, __shfl_xor(mx, off));

    float s = 0.f;
#pragma unroll
    for (int t = 0; t < 16; t++) { v[t] = __expf(v[t] - mx); s += v[t]; }
#pragma unroll
    for (int off = 32; off; off >>= 1) s += __shfl_xor(s, off);
    float inv = 1.f / s;

    u16* orow = attb + (size_t)bn * 1024 + lane * 16;
#pragma unroll
    for (int c = 0; c < 4; c++) {
        us4 o;
        o.x = f2bf(v[c * 4 + 0] * inv); o.y = f2bf(v[c * 4 + 1] * inv);
        o.z = f2bf(v[c * 4 + 2] * inv); o.w = f2bf(v[c * 4 + 3] * inv);
        *reinterpret_cast<us4*>(orow + c * 4) = o;
    }
}

extern "C" void kernel_launch(void* const* d_in, const int* in_sizes, int n_in,
                              void* d_out, int out_size, void* d_ws, size_t ws_size,
                              hipStream_t stream) {
    const float* x    = (const float*)d_in[0];
    const float* adj  = (const float*)d_in[1];
    const float* W_fc = (const float*)d_in[2];
    const float* b_fc = (const float*)d_in[3];
    const float* w_q  = (const float*)d_in[4];
    const float* b_q  = (const float*)d_in[5];
    const float* w_k  = (const float*)d_in[6];
    const float* b_k  = (const float*)d_in[7];
    const float* W_uy = (const float*)d_in[8];
    const float* b_uy = (const float*)d_in[9];
    const float* W_ux = (const float*)d_in[10];
    const float* b_ux = (const float*)d_in[11];
    const float* W_ry = (const float*)d_in[12];
    const float* b_ry = (const float*)d_in[13];
    const float* W_rx = (const float*)d_in[14];
    const float* b_rx = (const float*)d_in[15];
    const float* W_ty = (const float*)d_in[16];
    const float* b_ty = (const float*)d_in[17];
    const float* W_tx = (const float*)d_in[18];
    const float* b_tx = (const float*)d_in[19];

    char* ws = (char*)d_ws;
    u16*   CatA  = (u16*)  (ws + 0);            // 16384x1536 bf16  [y | x]   50331648
    u16*   Wfc_b = (u16*)  (ws + 50331648);     //  1179648
    u16*   Wty_b = (u16*)  (ws + 51511296);     //  1179648
    u16*   Wtx_b = (u16*)  (ws + 52690944);     //  1179648
    u16*   Wg    = (u16*)  (ws + 53870592);     // [ [Wuy|Wux] ; [Wry|Wrx] ] 4718592
    u16*   fpT   = (u16*)  (ws + 58589184);     // 16x768x1024 bf16          25165824
    float* qv    = (float*)(ws + 83755008);     // 16384 f32
    float* kv    = (float*)(ws + 83820544);     // 16384 f32
    u16*   attb  = (u16*)  (ws + 83886080);     // 16x1024x1024 bf16         33554432
    u16*   u_b   = (u16*)  (ws + 83886080);     // alias attb (dead after av)
    u16*   rxb   = (u16*)  (ws + 117440512);    // 16384x768 bf16            25165824

    cvtx<<<12288, 256, 0, stream>>>(x, CatA, qv);   // qv,kv contiguous: zeroes both

    WCvt wc;
    wc.s[0] = W_fc; wc.d[0] = Wfc_b;              wc.ld[0] = 768;
    wc.s[1] = W_ty; wc.d[1] = Wty_b;              wc.ld[1] = 768;
    wc.s[2] = W_tx; wc.d[2] = Wtx_b;              wc.ld[2] = 768;
    wc.s[3] = W_uy; wc.d[3] = Wg;                 wc.ld[3] = 1536;
    wc.s[4] = W_ux; wc.d[4] = Wg + 768;           wc.ld[4] = 1536;
    wc.s[5] = W_ry; wc.d[5] = Wg + 768 * 1536;    wc.ld[5] = 1536;
    wc.s[6] = W_rx; wc.d[6] = Wg + 768 * 1536 + 768; wc.ld[6] = 1536;
    cvtw<<<dim3(576, 7), 256, 0, stream>>>(wc);

    Epi e{};
    // feat_proj = x @ Wfc^T + b (A = CatA right half), + fused q/k partials
    e = Epi{}; e.b1 = b_fc; e.wq = w_q; e.wk = w_k; e.qv = qv; e.kv = kv; e.fpT = fpT;
    g128<EPI_FPT, 1><<<dim3(128, 6), 256, 0, stream>>>(CatA + 768, Wfc_b, nullptr, nullptr,
                                                       768, 1536, 768, 0, 0, 0, 0, e);

    k_soft4<<<4096, 256, 0, stream>>>(adj, qv, kv, b_q, b_k, attb);

    // y = att @ fp  -> CatA left half
    e = Epi{}; e.catA = CatA;
    g128<EPI_Y, 1><<<dim3(8, 6, 16), 256, 0, stream>>>(attb, fpT, nullptr, nullptr,
                                                       1024, 1024, 1024, 0, 0,
                                                       1048576, 786432, e);
    // gates: [u | r] = CatA @ [Wuy|Wux ; Wry|Wrx]^T
    e = Epi{}; e.b1 = b_uy; e.b2 = b_ux; e.b3 = b_ry; e.b4 = b_rx;
    e.xb = CatA + 768; e.ub_o = u_b; e.rxb_o = rxb;
    g128<EPI_GATES, 1><<<dim3(128, 12), 256, 0, stream>>>(CatA, Wg, nullptr, nullptr,
                                                          1536, 1536, 1536, 0, 0, 0, 0, e);
    // out = (1-u)x + u*tanh(y@Wty^T + rx@Wtx^T + b_ty + b_tx)
    e = Epi{}; e.b1 = b_ty; e.b2 = b_tx; e.ub = u_b; e.xb = CatA + 768; e.of = (float*)d_out;
    g128<EPI_OUT, 2><<<dim3(128, 6), 256, 0, stream>>>(CatA, Wty_b, rxb, Wtx_b,
                                                       768, 1536, 768, 768, 768, 0, 0, e);
}

// Round 5
// 447.192 us; speedup vs baseline: 2.3068x; 1.0349x over previous
//
#include <hip/hip_runtime.h>
#include <cmath>

typedef __attribute__((ext_vector_type(8))) short bf16x8;
typedef __attribute__((ext_vector_type(4))) float f32x4;
typedef unsigned short u16;

struct __align__(8) us4 { u16 x, y, z, w; };

__device__ __forceinline__ u16 f2bf(float f) {
    union { float f; unsigned u; } v; v.f = f;
    unsigned u = v.u;
    u += 0x7fffu + ((u >> 16) & 1u);   // RNE
    return (u16)(u >> 16);
}
__device__ __forceinline__ float bf2f(u16 h) {
    union { unsigned u; float f; } v; v.u = ((unsigned)h) << 16;
    return v.f;
}
__device__ __forceinline__ f32x4 mfma16(bf16x8 a, bf16x8 b, f32x4 c) {
    return __builtin_amdgcn_mfma_f32_16x16x32_bf16(a, b, c, 0, 0, 0);
}
__device__ __forceinline__ void ld_lds16(const u16* g, u16* l) {
    __builtin_amdgcn_global_load_lds(
        (const __attribute__((address_space(1))) unsigned int*)g,
        (__attribute__((address_space(3))) unsigned int*)l, 16, 0, 0);
}

// ---------------- x -> CatA right half (bf16) + zero qv/kv ----------------
__global__ __launch_bounds__(256) void cvtx(const float* __restrict__ in,
                                            u16* __restrict__ CatA, float* __restrict__ qkz) {
    int i = blockIdx.x * 256 + threadIdx.x;         // over 3145728 float4 groups
    float4 f = reinterpret_cast<const float4*>(in)[i];
    us4 o; o.x = f2bf(f.x); o.y = f2bf(f.y); o.z = f2bf(f.z); o.w = f2bf(f.w);
    int row = i / 192, col = (i % 192) * 4;
    *reinterpret_cast<us4*>(CatA + (size_t)row * 1536 + 768 + col) = o;
    if (i < 8192) reinterpret_cast<float4*>(qkz)[i] = float4{0.f, 0.f, 0.f, 0.f};
}

// ---------------- 7 weight converts in one dispatch ----------------
struct WCvt { const float* s[7]; u16* d[7]; int ld[7]; };
__global__ __launch_bounds__(256) void cvtw(WCvt w) {
    int wi = blockIdx.y;
    int i = blockIdx.x * 256 + threadIdx.x;         // over 147456 float4 groups
    float4 f = reinterpret_cast<const float4*>(w.s[wi])[i];
    us4 o; o.x = f2bf(f.x); o.y = f2bf(f.y); o.z = f2bf(f.z); o.w = f2bf(f.w);
    int row = i / 192, col = (i % 192) * 4;
    *reinterpret_cast<us4*>(w.d[wi] + (size_t)row * w.ld[wi] + col) = o;
}

// =====================================================================
// m97-style GEMM, 128x128 tile, BK=64 (halved barrier count vs BK=32),
// global_load_lds w16, XOR-by-(row&7) chunk swizzle (generalizes the
// round-3 swizzle that measured 0 bank conflicts). Optional 2nd phase
// accumulates A2 @ B2^T into the same accumulators.
// LDS: 2 x 16 KB. Occupancy: reg-limited ~3 blk/CU (unchanged).
// =====================================================================
enum { EPI_FPT = 0, EPI_Y, EPI_GATES, EPI_OUT };

struct Epi {
    const float* b1; const float* b2; const float* b3; const float* b4;
    const float* wq; const float* wk; float* qv; float* kv;   // FPT
    u16* fpT;
    u16* catA;                                                 // Y
    const u16* xb;        // CatA+768 (stride 1536)
    u16* ub_o; u16* rxb_o;                                     // GATES
    const u16* ub; float* of;                                  // OUT
};

template<int EPI, int PH>
__global__ __launch_bounds__(256) void g128(
    const u16* __restrict__ A1, const u16* __restrict__ B1,
    const u16* __restrict__ A2, const u16* __restrict__ B2,
    int K, int ldA1, int ldB1, int ldA2, int ldB2,
    size_t zA, size_t zB, Epi e)
{
    __shared__ u16 lA[128 * 64];
    __shared__ u16 lB[128 * 64];

    const int t = threadIdx.x;
    const int w = t >> 6, lane = t & 63, lm = lane & 15, quad = lane >> 4;
    const int row0 = blockIdx.x * 128;
    int col0, grp = 0;
    if constexpr (EPI == EPI_GATES) { grp = blockIdx.y / 6; col0 = (blockIdx.y % 6) * 128; }
    else col0 = blockIdx.y * 128;

    // staging: linear chunk-id n = q*256 + t; LDS offset = n*16B (fits
    // wave-uniform base + lane*16). Global: row = row0 + q*32 + (t>>3),
    // chunk = (t&7) ^ ((t>>3)&7)  [XOR swizzle vs row&7].
    const int rs2 = t >> 3;                         // 0..31
    const int kc2 = (((t & 7) ^ (rs2 & 7)) * 8);
    u16* dA_[4]; u16* dB_[4];
#pragma unroll
    for (int q = 0; q < 4; q++) {
        dA_[q] = lA + q * 2048 + w * 512;
        dB_[q] = lB + q * 2048 + w * 512;
    }

    // compute map: wave (w&1) row-half, (w>>1) col-half
    const int rw0 = (w & 1) * 64, cw0 = (w >> 1) * 64;
    // LDS read: row R, logical k-half h chunk (quad+4h); stored at chunk^( R&7 ), R&7 == lm&7
    const int ch0 = ((quad) ^ (lm & 7)) * 8;
    const int ch1 = ((quad + 4) ^ (lm & 7)) * 8;
    int laB[4], lbB[4];
#pragma unroll
    for (int i = 0; i < 4; i++) laB[i] = (rw0 + i * 16 + lm) * 64;
#pragma unroll
    for (int j = 0; j < 4; j++) lbB[j] = (cw0 + j * 16 + lm) * 64;

    f32x4 acc[4][4] = {};
    bool first = true;

#pragma unroll
    for (int ph = 0; ph < PH; ph++) {
        const u16* As; const u16* Bs; int ldA, ldB;
        if (ph == 0) { As = A1 + (size_t)blockIdx.z * zA; Bs = B1 + (size_t)blockIdx.z * zB; ldA = ldA1; ldB = ldB1; }
        else         { As = A2; Bs = B2; ldA = ldA2; ldB = ldB2; }
        if constexpr (EPI == EPI_GATES) Bs += (size_t)grp * (768 * 1536);
        const u16* gA = As + (size_t)(row0 + rs2) * ldA + kc2;
        const u16* gB = Bs + (size_t)(col0 + rs2) * ldB + kc2;

        for (int k0 = 0; k0 < K; k0 += 64) {
            if (!first) __syncthreads();
            first = false;
#pragma unroll
            for (int q = 0; q < 4; q++) {
                ld_lds16(gA + (size_t)(q * 32) * ldA + k0, dA_[q]);
                ld_lds16(gB + (size_t)(q * 32) * ldB + k0, dB_[q]);
            }
            __syncthreads();

#pragma unroll
            for (int h = 0; h < 2; h++) {
                const int ch = h ? ch1 : ch0;
                bf16x8 a[4], b[4];
#pragma unroll
                for (int i = 0; i < 4; i++) a[i] = *reinterpret_cast<const bf16x8*>(lA + laB[i] + ch);
#pragma unroll
                for (int j = 0; j < 4; j++) b[j] = *reinterpret_cast<const bf16x8*>(lB + lbB[j] + ch);
#pragma unroll
                for (int i = 0; i < 4; i++)
#pragma unroll
                    for (int j = 0; j < 4; j++)
                        acc[i][j] = mfma16(a[i], b[j], acc[i][j]);
            }
        }
    }

    // ---------------- epilogue ----------------
#pragma unroll
    for (int i = 0; i < 4; i++) {
        const int gr = row0 + rw0 + i * 16 + quad * 4;   // local (per-z) row
        if constexpr (EPI == EPI_FPT) {
            float qp[4] = {}, kp[4] = {};
            int bb = gr >> 10, nn = gr & 1023;
#pragma unroll
            for (int j = 0; j < 4; j++) {
                int gc = col0 + cw0 + j * 16 + lm;
                float bias = e.b1[gc];
                float v0 = acc[i][j][0] + bias, v1 = acc[i][j][1] + bias;
                float v2 = acc[i][j][2] + bias, v3 = acc[i][j][3] + bias;
                us4 o; o.x = f2bf(v0); o.y = f2bf(v1); o.z = f2bf(v2); o.w = f2bf(v3);
                *reinterpret_cast<us4*>(e.fpT + (size_t)bb * 786432 + (size_t)gc * 1024 + nn) = o;
                float wqv = e.wq[gc], wkv = e.wk[gc];
                qp[0] = fmaf(v0, wqv, qp[0]); qp[1] = fmaf(v1, wqv, qp[1]);
                qp[2] = fmaf(v2, wqv, qp[2]); qp[3] = fmaf(v3, wqv, qp[3]);
                kp[0] = fmaf(v0, wkv, kp[0]); kp[1] = fmaf(v1, wkv, kp[1]);
                kp[2] = fmaf(v2, wkv, kp[2]); kp[3] = fmaf(v3, wkv, kp[3]);
            }
#pragma unroll
            for (int r = 0; r < 4; r++) {
                float q = qp[r], k = kp[r];
#pragma unroll
                for (int m = 1; m < 16; m <<= 1) { q += __shfl_xor(q, m); k += __shfl_xor(k, m); }
                if (lm == 0) { atomicAdd(e.qv + gr + r, q); atomicAdd(e.kv + gr + r, k); }
            }
        } else if constexpr (EPI == EPI_Y) {
            size_t grow = (size_t)blockIdx.z * 1024 + gr;
#pragma unroll
            for (int j = 0; j < 4; j++) {
                int gc = col0 + cw0 + j * 16 + lm;
#pragma unroll
                for (int r = 0; r < 4; r++)
                    e.catA[(grow + r) * 1536 + gc] = f2bf(acc[i][j][r]);
            }
        } else if constexpr (EPI == EPI_GATES) {
#pragma unroll
            for (int j = 0; j < 4; j++) {
                int gc = col0 + cw0 + j * 16 + lm;
                if (grp == 0) {
                    float bias = e.b1[gc] + e.b2[gc];      // b_uy + b_ux
#pragma unroll
                    for (int r = 0; r < 4; r++) {
                        size_t idx = (size_t)(gr + r) * 768 + gc;
                        e.ub_o[idx] = f2bf(1.f / (1.f + __expf(-(acc[i][j][r] + bias))));
                    }
                } else {
                    float bias = e.b3[gc] + e.b4[gc];      // b_ry + b_rx
#pragma unroll
                    for (int r = 0; r < 4; r++) {
                        size_t idx = (size_t)(gr + r) * 768 + gc;
                        float rr = 1.f / (1.f + __expf(-(acc[i][j][r] + bias)));
                        float xv = bf2f(e.xb[(size_t)(gr + r) * 1536 + gc]);
                        e.rxb_o[idx] = f2bf(rr * xv);
                    }
                }
            }
        } else {  // EPI_OUT: acc = y@Wty + rx@Wtx
#pragma unroll
            for (int j = 0; j < 4; j++) {
                int gc = col0 + cw0 + j * 16 + lm;
                float bias = e.b1[gc] + e.b2[gc];          // b_ty + b_tx
#pragma unroll
                for (int r = 0; r < 4; r++) {
                    size_t idx = (size_t)(gr + r) * 768 + gc;
                    float tt = tanhf(acc[i][j][r] + bias);
                    float uu = bf2f(e.ub[idx]);
                    float xv = bf2f(e.xb[(size_t)(gr + r) * 1536 + gc]);
                    e.of[idx] = (1.f - uu) * xv + uu * tt;
                }
            }
        }
    }
}

// ---------------- softmax: one wave per row, shuffle-only reductions ----------------
__global__ __launch_bounds__(256) void k_soft4(const float* __restrict__ adj,
                                               const float* __restrict__ qv,
                                               const float* __restrict__ kv,
                                               const float* __restrict__ bq,
                                               const float* __restrict__ bk,
                                               u16* __restrict__ attb) {
    int wv = threadIdx.x >> 6, lane = threadIdx.x & 63;
    int bn = blockIdx.x * 4 + wv;
    int b = bn >> 10;
    const float* adjrow = adj + (size_t)bn * 1024 + lane * 16;
    const float* krow = kv + (b << 10) + lane * 16;
    float q = qv[bn] + bq[0] + bk[0];

    float v[16];
#pragma unroll
    for (int c = 0; c < 4; c++) {
        float4 a4 = *reinterpret_cast<const float4*>(adjrow + c * 4);
        float4 k4 = *reinterpret_cast<const float4*>(krow + c * 4);
        float* vv = v + c * 4;
        vv[0] = q + k4.x + (1.f - a4.x) * -1.0e9f;
        vv[1] = q + k4.y + (1.f - a4.y) * -1.0e9f;
        vv[2] = q + k4.z + (1.f - a4.z) * -1.0e9f;
        vv[3] = q + k4.w + (1.f - a4.w) * -1.0e9f;
    }
#pragma unroll
    for (int t = 0; t < 16; t++) v[t] = v[t] >= 0.f ? v[t] : 0.01f * v[t];

    float mx = v[0];
#pragma unroll
    for (int t = 1; t < 16; t++) mx = fmaxf(mx, v[t]);
#pragma unroll
    for (int off = 32; off; off >>= 1) mx = fmaxf(mx, __shfl_xor(mx, off));

    float s = 0.f;
#pragma unroll
    for (int t = 0; t < 16; t++) { v[t] = __expf(v[t] - mx); s += v[t]; }
#pragma unroll
    for (int off = 32; off; off >>= 1) s += __shfl_xor(s, off);
    float inv = 1.f / s;

    u16* orow = attb + (size_t)bn * 1024 + lane * 16;
#pragma unroll
    for (int c = 0; c < 4; c++) {
        us4 o;
        o.x = f2bf(v[c * 4 + 0] * inv); o.y = f2bf(v[c * 4 + 1] * inv);
        o.z = f2bf(v[c * 4 + 2] * inv); o.w = f2bf(v[c * 4 + 3] * inv);
        *reinterpret_cast<us4*>(orow + c * 4) = o;
    }
}

extern "C" void kernel_launch(void* const* d_in, const int* in_sizes, int n_in,
                              void* d_out, int out_size, void* d_ws, size_t ws_size,
                              hipStream_t stream) {
    const float* x    = (const float*)d_in[0];
    const float* adj  = (const float*)d_in[1];
    const float* W_fc = (const float*)d_in[2];
    const float* b_fc = (const float*)d_in[3];
    const float* w_q  = (const float*)d_in[4];
    const float* b_q  = (const float*)d_in[5];
    const float* w_k  = (const float*)d_in[6];
    const float* b_k  = (const float*)d_in[7];
    const float* W_uy = (const float*)d_in[8];
    const float* b_uy = (const float*)d_in[9];
    const float* W_ux = (const float*)d_in[10];
    const float* b_ux = (const float*)d_in[11];
    const float* W_ry = (const float*)d_in[12];
    const float* b_ry = (const float*)d_in[13];
    const float* W_rx = (const float*)d_in[14];
    const float* b_rx = (const float*)d_in[15];
    const float* W_ty = (const float*)d_in[16];
    const float* b_ty = (const float*)d_in[17];
    const float* W_tx = (const float*)d_in[18];
    const float* b_tx = (const float*)d_in[19];

    char* ws = (char*)d_ws;
    u16*   CatA  = (u16*)  (ws + 0);            // 16384x1536 bf16  [y | x]   50331648
    u16*   Wfc_b = (u16*)  (ws + 50331648);     //  1179648
    u16*   Wty_b = (u16*)  (ws + 51511296);     //  1179648
    u16*   Wtx_b = (u16*)  (ws + 52690944);     //  1179648
    u16*   Wg    = (u16*)  (ws + 53870592);     // [ [Wuy|Wux] ; [Wry|Wrx] ] 4718592
    u16*   fpT   = (u16*)  (ws + 58589184);     // 16x768x1024 bf16          25165824
    float* qv    = (float*)(ws + 83755008);     // 16384 f32
    float* kv    = (float*)(ws + 83820544);     // 16384 f32
    u16*   attb  = (u16*)  (ws + 83886080);     // 16x1024x1024 bf16         33554432
    u16*   u_b   = (u16*)  (ws + 83886080);     // alias attb (dead after av)
    u16*   rxb   = (u16*)  (ws + 117440512);    // 16384x768 bf16            25165824

    cvtx<<<12288, 256, 0, stream>>>(x, CatA, qv);   // qv,kv contiguous: zeroes both

    WCvt wc;
    wc.s[0] = W_fc; wc.d[0] = Wfc_b;              wc.ld[0] = 768;
    wc.s[1] = W_ty; wc.d[1] = Wty_b;              wc.ld[1] = 768;
    wc.s[2] = W_tx; wc.d[2] = Wtx_b;              wc.ld[2] = 768;
    wc.s[3] = W_uy; wc.d[3] = Wg;                 wc.ld[3] = 1536;
    wc.s[4] = W_ux; wc.d[4] = Wg + 768;           wc.ld[4] = 1536;
    wc.s[5] = W_ry; wc.d[5] = Wg + 768 * 1536;    wc.ld[5] = 1536;
    wc.s[6] = W_rx; wc.d[6] = Wg + 768 * 1536 + 768; wc.ld[6] = 1536;
    cvtw<<<dim3(576, 7), 256, 0, stream>>>(wc);

    Epi e{};
    // feat_proj = x @ Wfc^T + b (A = CatA right half), + fused q/k partials
    e = Epi{}; e.b1 = b_fc; e.wq = w_q; e.wk = w_k; e.qv = qv; e.kv = kv; e.fpT = fpT;
    g128<EPI_FPT, 1><<<dim3(128, 6), 256, 0, stream>>>(CatA + 768, Wfc_b, nullptr, nullptr,
                                                       768, 1536, 768, 0, 0, 0, 0, e);

    k_soft4<<<4096, 256, 0, stream>>>(adj, qv, kv, b_q, b_k, attb);

    // y = att @ fp  -> CatA left half
    e = Epi{}; e.catA = CatA;
    g128<EPI_Y, 1><<<dim3(8, 6, 16), 256, 0, stream>>>(attb, fpT, nullptr, nullptr,
                                                       1024, 1024, 1024, 0, 0,
                                                       1048576, 786432, e);
    // gates: [u | r] = CatA @ [Wuy|Wux ; Wry|Wrx]^T
    e = Epi{}; e.b1 = b_uy; e.b2 = b_ux; e.b3 = b_ry; e.b4 = b_rx;
    e.xb = CatA + 768; e.ub_o = u_b; e.rxb_o = rxb;
    g128<EPI_GATES, 1><<<dim3(128, 12), 256, 0, stream>>>(CatA, Wg, nullptr, nullptr,
                                                          1536, 1536, 1536, 0, 0, 0, 0, e);
    // out = (1-u)x + u*tanh(y@Wty^T + rx@Wtx^T + b_ty + b_tx)
    e = Epi{}; e.b1 = b_ty; e.b2 = b_tx; e.ub = u_b; e.xb = CatA + 768; e.of = (float*)d_out;
    g128<EPI_OUT, 2><<<dim3(128, 6), 256, 0, stream>>>(CatA, Wty_b, rxb, Wtx_b,
                                                       768, 1536, 768, 768, 768, 0, 0, e);
}